// Round 7
// baseline (72.621 us; speedup 1.0000x reference)
//
#include <hip/hip_runtime.h>
#include <math.h>
#include <stdint.h>

#define BQ 8
#define CC 256
#define HH 64
#define WW 64
#define LL 4096
#define AH 8
#define DD 32

typedef __attribute__((ext_vector_type(4))) float f32x4;
typedef __attribute__((ext_vector_type(8))) short short8;

__device__ __forceinline__ uint32_t pk_bf16(float a, float b) {
    uint32_t r;
    asm("v_cvt_pk_bf16_f32 %0, %1, %2" : "=v"(r) : "v"(a), "v"(b));
    return r;
}
__device__ __forceinline__ float bf_lo(uint32_t u) { return __uint_as_float(u << 16); }
__device__ __forceinline__ float bf_hi(uint32_t u) { return __uint_as_float(u & 0xffff0000u); }

__device__ __forceinline__ void split2(float a, float b, uint32_t& hi, uint32_t& lo) {
    hi = pk_bf16(a, b);
    float ah = bf_lo(hi), bh = bf_hi(hi);
    lo = pk_bf16(a - ah, b - bh);
}

// ---------------- shared GEMM building blocks ----------------
// LDS tile: rows x 32 uint32 (64 bf16) = 128B rows.
// 16B slot s of row r stored at slot s^(r&7) (XOR swizzle, conflict-free).

__device__ __forceinline__ void load8(float4 v[8], const float* p, size_t stride) {
#pragma unroll
    for (int i = 0; i < 8; ++i) v[i] = *(const float4*)(p + (size_t)i * stride);
}

__device__ __forceinline__ void writeA(const float4 av[8], uint32_t* as, int a_r0, int a_f4) {
#pragma unroll
    for (int i = 0; i < 8; ++i) {
        int r = a_r0 + i * 16;
        uint32_t lo = pk_bf16(av[i].x, av[i].y);
        uint32_t hi = pk_bf16(av[i].z, av[i].w);
        int slot = (a_f4 >> 1) ^ (r & 7);
        *(uint2*)&as[r * 32 + (slot << 2) + ((a_f4 & 1) << 1)] = make_uint2(lo, hi);
    }
}

__device__ __forceinline__ void writeB_x(const float4 bv[8], uint32_t* bs, int b_kb, int b_l0) {
#pragma unroll
    for (int j = 0; j < 4; ++j) {
        int l = b_l0 * 4 + j;
        uint32_t w0 = pk_bf16(((const float*)&bv[0])[j], ((const float*)&bv[1])[j]);
        uint32_t w1 = pk_bf16(((const float*)&bv[2])[j], ((const float*)&bv[3])[j]);
        uint32_t w2 = pk_bf16(((const float*)&bv[4])[j], ((const float*)&bv[5])[j]);
        uint32_t w3 = pk_bf16(((const float*)&bv[6])[j], ((const float*)&bv[7])[j]);
        int slot = b_kb ^ (l & 7);
        *(uint4*)&bs[l * 32 + (slot << 2)] = make_uint4(w0, w1, w2, w3);
    }
}

__device__ __forceinline__ void compute_tile(const uint32_t* as, const uint32_t* bs,
                                             f32x4 acc[4][4], int lane, int wm, int wn) {
#pragma unroll
    for (int ks = 0; ks < 2; ++ks) {
        int ag = ks * 4 + (lane >> 4);
        short8 af[4], bf[4];
#pragma unroll
        for (int mf = 0; mf < 4; ++mf) {
            int r = wm * 64 + mf * 16 + (lane & 15);
            af[mf] = *(const short8*)&as[r * 32 + ((ag ^ (r & 7)) << 2)];
        }
#pragma unroll
        for (int nf = 0; nf < 4; ++nf) {
            int r = wn * 64 + nf * 16 + (lane & 15);
            bf[nf] = *(const short8*)&bs[r * 32 + ((ag ^ (r & 7)) << 2)];
        }
#pragma unroll
        for (int mf = 0; mf < 4; ++mf)
#pragma unroll
            for (int nf = 0; nf < 4; ++nf)
                acc[mf][nf] = __builtin_amdgcn_mfma_f32_16x16x32_bf16(
                    af[mf], bf[nf], acc[mf][nf], 0, 0, 0);
    }
}

// ---------------------------------------------------------------------------
// pack_wout: w_out fp32 [256][256] -> bf16 fragments in MFMA order.
// ---------------------------------------------------------------------------
__global__ __launch_bounds__(256)
void pack_wout(const float* __restrict__ Wm, uint32_t* __restrict__ w_pack)
{
    int id = blockIdx.x * 256 + threadIdx.x;     // 0..8191
    int lane  = id & 63;
    int kc    = (id >> 6) & 7;
    int otile = id >> 9;
    int o  = otile * 16 + (lane & 15);
    int k0 = kc * 32 + (lane >> 4) * 8;
    const float* wp = Wm + (size_t)o * CC + k0;
    float4 v0 = *(const float4*)wp;
    float4 v1 = *(const float4*)(wp + 4);
    ((uint4*)w_pack)[id] = make_uint4(pk_bf16(v0.x, v0.y), pk_bf16(v0.z, v0.w),
                                      pk_bf16(v1.x, v1.y), pk_bf16(v1.z, v1.w));
}

// ---------------------------------------------------------------------------
// gemm_attoff: logits[b][o][l], o in [0,96): 0..31 att, 32..95 off.
// Split-bf16 MFMA (xh*wh + xh*wl + xl*wh). 96x64 tile, BK=64, dbuf.
// ---------------------------------------------------------------------------
__global__ __launch_bounds__(256, 2)
void gemm_attoff(const float* __restrict__ X,
                 const float* __restrict__ w_att, const float* __restrict__ w_off,
                 const float* __restrict__ b_att, const float* __restrict__ b_off,
                 float* __restrict__ outbuf)
{
    __shared__ uint32_t ah_s[2][96 * 32];
    __shared__ uint32_t al_s[2][96 * 32];
    __shared__ uint32_t bh_s[2][64 * 32];
    __shared__ uint32_t bl_s[2][64 * 32];

    const int lb = blockIdx.x;
    const int b  = blockIdx.y;
    const int t  = threadIdx.x;
    const int lane = t & 63;
    const int wv = t >> 6;
    const int wm = wv >> 1, wn = wv & 1;

    const int tr   = t >> 4;
    const int a_f4 = t & 15;
    const int b_kb = t & 7;
    const int b_l0 = t >> 3;

    const float* Bp = X + ((size_t)b * CC + b_kb * 8) * LL + lb * 64 + b_l0 * 2;

    f32x4 acc[3][2];
#pragma unroll
    for (int i = 0; i < 3; ++i)
#pragma unroll
        for (int j = 0; j < 2; ++j) acc[i][j] = (f32x4)0.0f;

    float4 av[6];
    float2 bv[8];

    auto loadT = [&](int kc) {
#pragma unroll
        for (int i = 0; i < 6; ++i) {
            int r = i * 16 + tr;
            const float* wp = (i < 2) ? (w_att + (size_t)r * CC)
                                      : (w_off + (size_t)(r - 32) * CC);
            av[i] = *(const float4*)(wp + kc * 64 + a_f4 * 4);
        }
#pragma unroll
        for (int m = 0; m < 8; ++m)
            bv[m] = *(const float2*)(Bp + (size_t)(kc * 64 + m) * LL);
    };

    auto writeT = [&](int buf) {
#pragma unroll
        for (int i = 0; i < 6; ++i) {
            int r = i * 16 + tr;
            uint32_t h0, q0, h1, q1;
            split2(av[i].x, av[i].y, h0, q0);
            split2(av[i].z, av[i].w, h1, q1);
            int idx = r * 32 + (((a_f4 >> 1) ^ (r & 7)) << 2) + ((a_f4 & 1) << 1);
            *(uint2*)&ah_s[buf][idx] = make_uint2(h0, h1);
            *(uint2*)&al_s[buf][idx] = make_uint2(q0, q1);
        }
#pragma unroll
        for (int j = 0; j < 2; ++j) {
            int l = b_l0 * 2 + j;
            uint32_t h[4], q[4];
#pragma unroll
            for (int p = 0; p < 4; ++p) {
                float e0 = j ? bv[2 * p].y     : bv[2 * p].x;
                float e1 = j ? bv[2 * p + 1].y : bv[2 * p + 1].x;
                split2(e0, e1, h[p], q[p]);
            }
            int idx = l * 32 + ((b_kb ^ (l & 7)) << 2);
            *(uint4*)&bh_s[buf][idx] = make_uint4(h[0], h[1], h[2], h[3]);
            *(uint4*)&bl_s[buf][idx] = make_uint4(q[0], q[1], q[2], q[3]);
        }
    };

    auto computeT = [&](int buf) {
#pragma unroll
        for (int ks = 0; ks < 2; ++ks) {
            int ag = ks * 4 + (lane >> 4);
            short8 afh[3], afl[3], bfh[2], bfl[2];
#pragma unroll
            for (int mf = 0; mf < 3; ++mf) {
                int r = wm * 48 + mf * 16 + (lane & 15);
                int off = r * 32 + ((ag ^ (r & 7)) << 2);
                afh[mf] = *(const short8*)&ah_s[buf][off];
                afl[mf] = *(const short8*)&al_s[buf][off];
            }
#pragma unroll
            for (int nf = 0; nf < 2; ++nf) {
                int r = wn * 32 + nf * 16 + (lane & 15);
                int off = r * 32 + ((ag ^ (r & 7)) << 2);
                bfh[nf] = *(const short8*)&bh_s[buf][off];
                bfl[nf] = *(const short8*)&bl_s[buf][off];
            }
#pragma unroll
            for (int mf = 0; mf < 3; ++mf)
#pragma unroll
                for (int nf = 0; nf < 2; ++nf) {
                    acc[mf][nf] = __builtin_amdgcn_mfma_f32_16x16x32_bf16(
                        afh[mf], bfh[nf], acc[mf][nf], 0, 0, 0);
                    acc[mf][nf] = __builtin_amdgcn_mfma_f32_16x16x32_bf16(
                        afh[mf], bfl[nf], acc[mf][nf], 0, 0, 0);
                    acc[mf][nf] = __builtin_amdgcn_mfma_f32_16x16x32_bf16(
                        afl[mf], bfh[nf], acc[mf][nf], 0, 0, 0);
                }
        }
    };

    loadT(0);
    writeT(0);
    __syncthreads();
    for (int kc = 0; kc < 4; ++kc) {
        const int cur = kc & 1;
        if (kc < 3) loadT(kc + 1);
        computeT(cur);
        if (kc < 3) { writeT(cur ^ 1); __syncthreads(); }
    }

    const int l_base = lb * 64 + wn * 32 + (lane & 15);
    const int o_base = wm * 48 + ((lane >> 4) << 2);
#pragma unroll
    for (int mf = 0; mf < 3; ++mf) {
        int o0 = o_base + mf * 16;
        const float* bp = (o0 < 32) ? (b_att + o0) : (b_off + (o0 - 32));
        float4 bs = *(const float4*)bp;
#pragma unroll
        for (int nf = 0; nf < 2; ++nf) {
            int l = l_base + nf * 16;
            float* op = outbuf + ((size_t)b * 96 + o0) * LL + l;
            op[(size_t)0 * LL] = acc[mf][nf][0] + bs.x;
            op[(size_t)1 * LL] = acc[mf][nf][1] + bs.y;
            op[(size_t)2 * LL] = acc[mf][nf][2] + bs.z;
            op[(size_t)3 * LL] = acc[mf][nf][3] + bs.w;
        }
    }
}

// ---------------------------------------------------------------------------
// gemm_v: v[b][o][l] -> bf16 [(b*8+o/32)][l][o%32]  (into ws)
// ---------------------------------------------------------------------------
__global__ __launch_bounds__(256, 2)
void gemm_v(const float* __restrict__ X, const float* __restrict__ Wm,
            const float* __restrict__ bias, uint16_t* __restrict__ vout)
{
    __shared__ uint32_t a_s[2][128 * 32];
    __shared__ uint32_t b_s[2][128 * 32];

    const int nb = blockIdx.x;
    const int b  = nb >> 5;
    const int lb = nb & 31;
    const int ob = blockIdx.y;
    const int t  = threadIdx.x;
    const int lane = t & 63;
    const int wv = t >> 6;
    const int wm = wv >> 1, wn = wv & 1;

    const int a_f4 = t & 15, a_r0 = t >> 4;
    const int b_kb = t & 7,  b_l0 = t >> 3;

    const float* Ap = Wm + (size_t)(ob * 128 + a_r0) * CC + a_f4 * 4;
    const float* Bp = X + ((size_t)b * CC + b_kb * 8) * LL + lb * 128 + b_l0 * 4;

    f32x4 acc[4][4];
#pragma unroll
    for (int i = 0; i < 4; ++i)
#pragma unroll
        for (int j = 0; j < 4; ++j) acc[i][j] = (f32x4)0.0f;

    float4 av[8], bv[8];
    load8(av, Ap, (size_t)16 * CC);
    load8(bv, Bp, (size_t)LL);
    writeA(av, a_s[0], a_r0, a_f4);
    writeB_x(bv, b_s[0], b_kb, b_l0);
    __syncthreads();

    for (int kc = 0; kc < 4; ++kc) {
        const int cur = kc & 1;
        if (kc < 3) {
            load8(av, Ap + (kc + 1) * 64, (size_t)16 * CC);
            load8(bv, Bp + (size_t)(kc + 1) * 64 * LL, (size_t)LL);
        }
        compute_tile(a_s[cur], b_s[cur], acc, lane, wm, wn);
        if (kc < 3) {
            writeA(av, a_s[cur ^ 1], a_r0, a_f4);
            writeB_x(bv, b_s[cur ^ 1], b_kb, b_l0);
            __syncthreads();
        }
    }

    const int l_base = lb * 128 + wn * 64 + (lane & 15);
    const int o_base = ob * 128 + wm * 64 + ((lane >> 4) << 2);
#pragma unroll
    for (int mf = 0; mf < 4; ++mf) {
        int o0 = o_base + mf * 16;
        float4 bs = *(const float4*)(bias + o0);
        int a_h = o0 >> 5;
        int d0 = o0 & 31;
#pragma unroll
        for (int nf = 0; nf < 4; ++nf) {
            int l = l_base + nf * 16;
            uint32_t p0 = pk_bf16(acc[mf][nf][0] + bs.x, acc[mf][nf][1] + bs.y);
            uint32_t p1 = pk_bf16(acc[mf][nf][2] + bs.z, acc[mf][nf][3] + bs.w);
            *(uint2*)(vout + ((size_t)(b * AH + a_h) * LL + l) * DD + d0) =
                make_uint2(p0, p1);
        }
    }
}

// ---------------------------------------------------------------------------
// Fused: softmax + offsets + bilinear sample + out-projection.
// Grid 1024 = (b = bid&7 [XCD-pinned], lt = bid>>3: 128 tiles of 32 points).
// Phase 1 (r5-style coalescing): thread = (head-pair hp = t>>7, point
// pt=(t>>2)&31, chan-group cg=t&3); 4 lanes share a point's 128B v-line;
// loop over 4 heads (a = hp*4+hi). Agg tile [32 l][256 c] bf16 in LDS.
// Phase 2: wave wv -> o rows 64*wv..+63 x 32 l, K=256 from LDS + packed W.
// ---------------------------------------------------------------------------
__global__ __launch_bounds__(256, 4)
void sample_out(const uint16_t* __restrict__ v_samp,
                const float* __restrict__ logits,
                const uint32_t* __restrict__ w_pack,
                const float* __restrict__ bias,
                float* __restrict__ out)
{
    __shared__ uint32_t agg_s[32 * 128];   // 16 KB

    const int bid = blockIdx.x;
    const int b   = bid & 7;
    const int lt  = bid >> 3;              // 0..127
    const int t   = threadIdx.x;
    const int lane = t & 63;
    const int wv  = t >> 6;

    const int hp = t >> 7;                 // 0..1
    const int pt = (t >> 2) & 31;          // 0..31
    const int cg = t & 3;                  // 0..3
    const int l  = lt * 32 + pt;
    const int gi = l >> 6, gj = l & 63;
    const float ry = (gi + 0.5f) * (2.0f / 63.0f) - 1.0f;
    const float rx = (gj + 0.5f) * (2.0f / 63.0f) - 1.0f;

    // ---------------- phase 1: sample; 4 heads per thread ----------------
#pragma unroll
    for (int hi = 0; hi < 4; ++hi) {
        const int a = hp * 4 + hi;

        const float* la = logits + ((size_t)b * 96 + a * 4) * LL + l;
        float e0 = la[0], e1 = la[(size_t)LL], e2 = la[(size_t)2 * LL], e3 = la[(size_t)3 * LL];
        float m = fmaxf(fmaxf(e0, e1), fmaxf(e2, e3));
        e0 = expf(e0 - m); e1 = expf(e1 - m); e2 = expf(e2 - m); e3 = expf(e3 - m);
        float inv = 1.0f / (e0 + e1 + e2 + e3);
        float attn[4] = {e0 * inv, e1 * inv, e2 * inv, e3 * inv};

        const float* lo = logits + ((size_t)b * 96 + 32 + a * 8) * LL + l;
        float pyy[4], pxx[4];
#pragma unroll
        for (int n = 0; n < 4; ++n) {
            pyy[n] = ry + lo[(size_t)(n * 2 + 0) * LL];
            pxx[n] = rx + lo[(size_t)(n * 2 + 1) * LL];
        }

        float acc[8];
#pragma unroll
        for (int q = 0; q < 8; ++q) acc[q] = 0.f;

        const uint16_t* vb = v_samp + (size_t)(b * AH + a) * LL * DD + cg * 8;
#pragma unroll
        for (int n = 0; n < 4; ++n) {
            float y = (pyy[n] + 1.0f) * 0.5f * 63.0f;
            float x = (pxx[n] + 1.0f) * 0.5f * 63.0f;
            float yf = floorf(y), xf = floorf(x);
            int y0i = (int)yf, x0i = (int)xf;
            float fy = y - yf, fx = x - xf;
            float wts[4] = {(1.f - fy) * (1.f - fx), (1.f - fy) * fx,
                            fy * (1.f - fx),         fy * fx};
            int yy[4] = {y0i, y0i, y0i + 1, y0i + 1};
            int xx[4] = {x0i, x0i + 1, x0i, x0i + 1};
#pragma unroll
            for (int c2 = 0; c2 < 4; ++c2) {
                int yc = yy[c2], xc = xx[c2];
                if (yc >= 0 && yc < HH && xc >= 0 && xc < WW) {
                    float w = attn[n] * wts[c2];
                    uint4 rv = *(const uint4*)(vb + (size_t)(yc * WW + xc) * DD);
                    acc[0] += w * bf_lo(rv.x); acc[1] += w * bf_hi(rv.x);
                    acc[2] += w * bf_lo(rv.y); acc[3] += w * bf_hi(rv.y);
                    acc[4] += w * bf_lo(rv.z); acc[5] += w * bf_hi(rv.z);
                    acc[6] += w * bf_lo(rv.w); acc[7] += w * bf_hi(rv.w);
                }
            }
        }
        // 8 channels -> one 16B slot of row pt; slot sl = a*4+cg, swizzled
        uint32_t p0 = pk_bf16(acc[0], acc[1]);
        uint32_t p1 = pk_bf16(acc[2], acc[3]);
        uint32_t p2 = pk_bf16(acc[4], acc[5]);
        uint32_t p3 = pk_bf16(acc[6], acc[7]);
        int sl = a * 4 + cg;
        *(uint4*)&agg_s[pt * 128 + ((sl ^ (pt & 7)) << 2)] =
            make_uint4(p0, p1, p2, p3);
    }
    __syncthreads();

    // ---------------- phase 2: out-projection (256 x 32 x 256) ----------------
    f32x4 acc2[4][2];
#pragma unroll
    for (int i = 0; i < 4; ++i)
#pragma unroll
        for (int j = 0; j < 2; ++j) acc2[i][j] = (f32x4)0.0f;

    for (int kc = 0; kc < 8; ++kc) {
        short8 af[4], bf[2];
#pragma unroll
        for (int mf = 0; mf < 4; ++mf) {
            int otile = wv * 4 + mf;
            af[mf] = *(const short8*)&w_pack[(size_t)((otile * 8 + kc) * 64 + lane) * 4];
        }
#pragma unroll
        for (int nf = 0; nf < 2; ++nf) {
            int r = nf * 16 + (lane & 15);
            int slot = kc * 4 + (lane >> 4);
            bf[nf] = *(const short8*)&agg_s[r * 128 + ((slot ^ (r & 7)) << 2)];
        }
#pragma unroll
        for (int mf = 0; mf < 4; ++mf)
#pragma unroll
            for (int nf = 0; nf < 2; ++nf)
                acc2[mf][nf] = __builtin_amdgcn_mfma_f32_16x16x32_bf16(
                    af[mf], bf[nf], acc2[mf][nf], 0, 0, 0);
    }

#pragma unroll
    for (int mf = 0; mf < 4; ++mf) {
        int o0 = wv * 64 + mf * 16 + ((lane >> 4) << 2);
        float4 bs = *(const float4*)(bias + o0);
#pragma unroll
        for (int nf = 0; nf < 2; ++nf) {
            int lx = lt * 32 + nf * 16 + (lane & 15);
            float* op = out + ((size_t)b * CC + o0) * LL + lx;
            op[(size_t)0 * LL] = acc2[mf][nf][0] + bs.x;
            op[(size_t)1 * LL] = acc2[mf][nf][1] + bs.y;
            op[(size_t)2 * LL] = acc2[mf][nf][2] + bs.z;
            op[(size_t)3 * LL] = acc2[mf][nf][3] + bs.w;
        }
    }
}

extern "C" void kernel_launch(void* const* d_in, const int* in_sizes, int n_in,
                              void* d_out, int out_size, void* d_ws, size_t ws_size,
                              hipStream_t stream) {
    const float* x     = (const float*)d_in[0];
    const float* w_att = (const float*)d_in[1];
    const float* b_att = (const float*)d_in[2];
    const float* w_off = (const float*)d_in[3];
    const float* b_off = (const float*)d_in[4];
    const float* w_v   = (const float*)d_in[5];
    const float* b_v   = (const float*)d_in[6];
    const float* w_out = (const float*)d_in[7];
    const float* b_out = (const float*)d_in[8];
    float* out = (float*)d_out;

    float* ws        = (float*)d_ws;
    float* logits    = ws;                                          // B*96*L f32 (12.6 MB)
    uint16_t* v_samp = (uint16_t*)(logits + (size_t)BQ * 96 * LL);  // B*A*L*32 bf16 (16.8 MB)
    uint32_t* w_pack = (uint32_t*)(v_samp + (size_t)BQ * AH * LL * DD); // 128 KB

    dim3 blk(256);
    pack_wout<<<dim3(32), blk, 0, stream>>>(w_out, w_pack);
    gemm_attoff<<<dim3(64, BQ), blk, 0, stream>>>(x, w_att, w_off, b_att, b_off, logits);
    gemm_v<<<dim3(256, 2), blk, 0, stream>>>(x, w_v, b_v, v_samp);
    sample_out<<<dim3(1024), blk, 0, stream>>>(v_samp, logits, w_pack, b_out, out);
}

// Round 8
// 65.105 us; speedup vs baseline: 1.1154x; 1.1154x over previous
//
#include <hip/hip_runtime.h>
#include <math.h>
#include <stdint.h>

#define BQ 8
#define CC 256
#define HH 64
#define WW 64
#define LL 4096
#define AH 8
#define DD 32

typedef __attribute__((ext_vector_type(4))) float f32x4;
typedef __attribute__((ext_vector_type(8))) short short8;

__device__ __forceinline__ uint32_t pk_bf16(float a, float b) {
    uint32_t r;
    asm("v_cvt_pk_bf16_f32 %0, %1, %2" : "=v"(r) : "v"(a), "v"(b));
    return r;
}
__device__ __forceinline__ float bf_lo(uint32_t u) { return __uint_as_float(u << 16); }
__device__ __forceinline__ float bf_hi(uint32_t u) { return __uint_as_float(u & 0xffff0000u); }

__device__ __forceinline__ void split2(float a, float b, uint32_t& hi, uint32_t& lo) {
    hi = pk_bf16(a, b);
    float ah = bf_lo(hi), bh = bf_hi(hi);
    lo = pk_bf16(a - ah, b - bh);
}

// ---------------- shared GEMM building blocks ----------------
// LDS tile: rows x 32 uint32 (64 bf16) = 128B rows.
// 16B slot s of row r stored at slot s^(r&7) (XOR swizzle, conflict-free).

__device__ __forceinline__ void load8(float4 v[8], const float* p, size_t stride) {
#pragma unroll
    for (int i = 0; i < 8; ++i) v[i] = *(const float4*)(p + (size_t)i * stride);
}

__device__ __forceinline__ void writeA(const float4 av[8], uint32_t* as, int a_r0, int a_f4) {
#pragma unroll
    for (int i = 0; i < 8; ++i) {
        int r = a_r0 + i * 16;
        uint32_t lo = pk_bf16(av[i].x, av[i].y);
        uint32_t hi = pk_bf16(av[i].z, av[i].w);
        int slot = (a_f4 >> 1) ^ (r & 7);
        *(uint2*)&as[r * 32 + (slot << 2) + ((a_f4 & 1) << 1)] = make_uint2(lo, hi);
    }
}

__device__ __forceinline__ void writeB_x(const float4 bv[8], uint32_t* bs, int b_kb, int b_l0) {
#pragma unroll
    for (int j = 0; j < 4; ++j) {
        int l = b_l0 * 4 + j;
        uint32_t w0 = pk_bf16(((const float*)&bv[0])[j], ((const float*)&bv[1])[j]);
        uint32_t w1 = pk_bf16(((const float*)&bv[2])[j], ((const float*)&bv[3])[j]);
        uint32_t w2 = pk_bf16(((const float*)&bv[4])[j], ((const float*)&bv[5])[j]);
        uint32_t w3 = pk_bf16(((const float*)&bv[6])[j], ((const float*)&bv[7])[j]);
        int slot = b_kb ^ (l & 7);
        *(uint4*)&bs[l * 32 + (slot << 2)] = make_uint4(w0, w1, w2, w3);
    }
}

__device__ __forceinline__ void compute_tile(const uint32_t* as, const uint32_t* bs,
                                             f32x4 acc[4][4], int lane, int wm, int wn) {
#pragma unroll
    for (int ks = 0; ks < 2; ++ks) {
        int ag = ks * 4 + (lane >> 4);
        short8 af[4], bf[4];
#pragma unroll
        for (int mf = 0; mf < 4; ++mf) {
            int r = wm * 64 + mf * 16 + (lane & 15);
            af[mf] = *(const short8*)&as[r * 32 + ((ag ^ (r & 7)) << 2)];
        }
#pragma unroll
        for (int nf = 0; nf < 4; ++nf) {
            int r = wn * 64 + nf * 16 + (lane & 15);
            bf[nf] = *(const short8*)&bs[r * 32 + ((ag ^ (r & 7)) << 2)];
        }
#pragma unroll
        for (int mf = 0; mf < 4; ++mf)
#pragma unroll
            for (int nf = 0; nf < 4; ++nf)
                acc[mf][nf] = __builtin_amdgcn_mfma_f32_16x16x32_bf16(
                    af[mf], bf[nf], acc[mf][nf], 0, 0, 0);
    }
}

// ---------------------------------------------------------------------------
// gemm_attoff: logits[b][o][l], o in [0,96): 0..31 att, 32..95 off.
// Split-bf16 MFMA (xh*wh + xh*wl + xl*wh). 96x64 tile, BK=64, dbuf.
// ---------------------------------------------------------------------------
__global__ __launch_bounds__(256, 2)
void gemm_attoff(const float* __restrict__ X,
                 const float* __restrict__ w_att, const float* __restrict__ w_off,
                 const float* __restrict__ b_att, const float* __restrict__ b_off,
                 float* __restrict__ outbuf)
{
    __shared__ uint32_t ah_s[2][96 * 32];
    __shared__ uint32_t al_s[2][96 * 32];
    __shared__ uint32_t bh_s[2][64 * 32];
    __shared__ uint32_t bl_s[2][64 * 32];

    const int lb = blockIdx.x;
    const int b  = blockIdx.y;
    const int t  = threadIdx.x;
    const int lane = t & 63;
    const int wv = t >> 6;
    const int wm = wv >> 1, wn = wv & 1;

    const int tr   = t >> 4;
    const int a_f4 = t & 15;
    const int b_kb = t & 7;
    const int b_l0 = t >> 3;

    const float* Bp = X + ((size_t)b * CC + b_kb * 8) * LL + lb * 64 + b_l0 * 2;

    f32x4 acc[3][2];
#pragma unroll
    for (int i = 0; i < 3; ++i)
#pragma unroll
        for (int j = 0; j < 2; ++j) acc[i][j] = (f32x4)0.0f;

    float4 av[6];
    float2 bv[8];

    auto loadT = [&](int kc) {
#pragma unroll
        for (int i = 0; i < 6; ++i) {
            int r = i * 16 + tr;
            const float* wp = (i < 2) ? (w_att + (size_t)r * CC)
                                      : (w_off + (size_t)(r - 32) * CC);
            av[i] = *(const float4*)(wp + kc * 64 + a_f4 * 4);
        }
#pragma unroll
        for (int m = 0; m < 8; ++m)
            bv[m] = *(const float2*)(Bp + (size_t)(kc * 64 + m) * LL);
    };

    auto writeT = [&](int buf) {
#pragma unroll
        for (int i = 0; i < 6; ++i) {
            int r = i * 16 + tr;
            uint32_t h0, q0, h1, q1;
            split2(av[i].x, av[i].y, h0, q0);
            split2(av[i].z, av[i].w, h1, q1);
            int idx = r * 32 + (((a_f4 >> 1) ^ (r & 7)) << 2) + ((a_f4 & 1) << 1);
            *(uint2*)&ah_s[buf][idx] = make_uint2(h0, h1);
            *(uint2*)&al_s[buf][idx] = make_uint2(q0, q1);
        }
#pragma unroll
        for (int j = 0; j < 2; ++j) {
            int l = b_l0 * 2 + j;
            uint32_t h[4], q[4];
#pragma unroll
            for (int p = 0; p < 4; ++p) {
                float e0 = j ? bv[2 * p].y     : bv[2 * p].x;
                float e1 = j ? bv[2 * p + 1].y : bv[2 * p + 1].x;
                split2(e0, e1, h[p], q[p]);
            }
            int idx = l * 32 + ((b_kb ^ (l & 7)) << 2);
            *(uint4*)&bh_s[buf][idx] = make_uint4(h[0], h[1], h[2], h[3]);
            *(uint4*)&bl_s[buf][idx] = make_uint4(q[0], q[1], q[2], q[3]);
        }
    };

    auto computeT = [&](int buf) {
#pragma unroll
        for (int ks = 0; ks < 2; ++ks) {
            int ag = ks * 4 + (lane >> 4);
            short8 afh[3], afl[3], bfh[2], bfl[2];
#pragma unroll
            for (int mf = 0; mf < 3; ++mf) {
                int r = wm * 48 + mf * 16 + (lane & 15);
                int off = r * 32 + ((ag ^ (r & 7)) << 2);
                afh[mf] = *(const short8*)&ah_s[buf][off];
                afl[mf] = *(const short8*)&al_s[buf][off];
            }
#pragma unroll
            for (int nf = 0; nf < 2; ++nf) {
                int r = wn * 32 + nf * 16 + (lane & 15);
                int off = r * 32 + ((ag ^ (r & 7)) << 2);
                bfh[nf] = *(const short8*)&bh_s[buf][off];
                bfl[nf] = *(const short8*)&bl_s[buf][off];
            }
#pragma unroll
            for (int mf = 0; mf < 3; ++mf)
#pragma unroll
                for (int nf = 0; nf < 2; ++nf) {
                    acc[mf][nf] = __builtin_amdgcn_mfma_f32_16x16x32_bf16(
                        afh[mf], bfh[nf], acc[mf][nf], 0, 0, 0);
                    acc[mf][nf] = __builtin_amdgcn_mfma_f32_16x16x32_bf16(
                        afh[mf], bfl[nf], acc[mf][nf], 0, 0, 0);
                    acc[mf][nf] = __builtin_amdgcn_mfma_f32_16x16x32_bf16(
                        afl[mf], bfh[nf], acc[mf][nf], 0, 0, 0);
                }
        }
    };

    loadT(0);
    writeT(0);
    __syncthreads();
    for (int kc = 0; kc < 4; ++kc) {
        const int cur = kc & 1;
        if (kc < 3) loadT(kc + 1);
        computeT(cur);
        if (kc < 3) { writeT(cur ^ 1); __syncthreads(); }
    }

    const int l_base = lb * 64 + wn * 32 + (lane & 15);
    const int o_base = wm * 48 + ((lane >> 4) << 2);
#pragma unroll
    for (int mf = 0; mf < 3; ++mf) {
        int o0 = o_base + mf * 16;
        const float* bp = (o0 < 32) ? (b_att + o0) : (b_off + (o0 - 32));
        float4 bs = *(const float4*)bp;
#pragma unroll
        for (int nf = 0; nf < 2; ++nf) {
            int l = l_base + nf * 16;
            float* op = outbuf + ((size_t)b * 96 + o0) * LL + l;
            op[(size_t)0 * LL] = acc[mf][nf][0] + bs.x;
            op[(size_t)1 * LL] = acc[mf][nf][1] + bs.y;
            op[(size_t)2 * LL] = acc[mf][nf][2] + bs.z;
            op[(size_t)3 * LL] = acc[mf][nf][3] + bs.w;
        }
    }
}

// ---------------------------------------------------------------------------
// gemm_v: v[b][o][l] -> bf16 [(b*8+o/32)][l][o%32]
// ---------------------------------------------------------------------------
__global__ __launch_bounds__(256, 2)
void gemm_v(const float* __restrict__ X, const float* __restrict__ Wm,
            const float* __restrict__ bias, uint16_t* __restrict__ vout)
{
    __shared__ uint32_t a_s[2][128 * 32];
    __shared__ uint32_t b_s[2][128 * 32];

    const int nb = blockIdx.x;
    const int b  = nb >> 5;
    const int lb = nb & 31;
    const int ob = blockIdx.y;
    const int t  = threadIdx.x;
    const int lane = t & 63;
    const int wv = t >> 6;
    const int wm = wv >> 1, wn = wv & 1;

    const int a_f4 = t & 15, a_r0 = t >> 4;
    const int b_kb = t & 7,  b_l0 = t >> 3;

    const float* Ap = Wm + (size_t)(ob * 128 + a_r0) * CC + a_f4 * 4;
    const float* Bp = X + ((size_t)b * CC + b_kb * 8) * LL + lb * 128 + b_l0 * 4;

    f32x4 acc[4][4];
#pragma unroll
    for (int i = 0; i < 4; ++i)
#pragma unroll
        for (int j = 0; j < 4; ++j) acc[i][j] = (f32x4)0.0f;

    float4 av[8], bv[8];
    load8(av, Ap, (size_t)16 * CC);
    load8(bv, Bp, (size_t)LL);
    writeA(av, a_s[0], a_r0, a_f4);
    writeB_x(bv, b_s[0], b_kb, b_l0);
    __syncthreads();

    for (int kc = 0; kc < 4; ++kc) {
        const int cur = kc & 1;
        if (kc < 3) {
            load8(av, Ap + (kc + 1) * 64, (size_t)16 * CC);
            load8(bv, Bp + (size_t)(kc + 1) * 64 * LL, (size_t)LL);
        }
        compute_tile(a_s[cur], b_s[cur], acc, lane, wm, wn);
        if (kc < 3) {
            writeA(av, a_s[cur ^ 1], a_r0, a_f4);
            writeB_x(bv, b_s[cur ^ 1], b_kb, b_l0);
            __syncthreads();
        }
    }

    const int l_base = lb * 128 + wn * 64 + (lane & 15);
    const int o_base = ob * 128 + wm * 64 + ((lane >> 4) << 2);
#pragma unroll
    for (int mf = 0; mf < 4; ++mf) {
        int o0 = o_base + mf * 16;
        float4 bs = *(const float4*)(bias + o0);
        int a_h = o0 >> 5;
        int d0 = o0 & 31;
#pragma unroll
        for (int nf = 0; nf < 4; ++nf) {
            int l = l_base + nf * 16;
            uint32_t p0 = pk_bf16(acc[mf][nf][0] + bs.x, acc[mf][nf][1] + bs.y);
            uint32_t p1 = pk_bf16(acc[mf][nf][2] + bs.z, acc[mf][nf][3] + bs.w);
            *(uint2*)(vout + ((size_t)(b * AH + a_h) * LL + l) * DD + d0) =
                make_uint2(p0, p1);
        }
    }
}

// ---------------------------------------------------------------------------
// gemm_out: y[b][o][l] = sum_c Wout[o][c]*agg_bf16[b][l][c] + bias, fp32 out.
// ---------------------------------------------------------------------------
__global__ __launch_bounds__(256, 2)
void gemm_out(const uint16_t* __restrict__ Agg, const float* __restrict__ Wm,
              const float* __restrict__ bias, float* __restrict__ out)
{
    __shared__ uint32_t a_s[2][128 * 32];
    __shared__ uint32_t b_s[2][128 * 32];

    const int nb = blockIdx.x;
    const int b  = nb >> 5;
    const int lb = nb & 31;
    const int ob = blockIdx.y;
    const int t  = threadIdx.x;
    const int lane = t & 63;
    const int wv = t >> 6;
    const int wm = wv >> 1, wn = wv & 1;

    const int a_f4 = t & 15, a_r0 = t >> 4;
    const int br = t >> 1;
    const int bh = t & 1;

    const float* Ap = Wm + (size_t)(ob * 128 + a_r0) * CC + a_f4 * 4;
    const uint16_t* Bp = Agg + ((size_t)b * LL + lb * 128 + br) * CC + bh * 32;

    f32x4 acc[4][4];
#pragma unroll
    for (int i = 0; i < 4; ++i)
#pragma unroll
        for (int j = 0; j < 4; ++j) acc[i][j] = (f32x4)0.0f;

    float4 av[8];
    uint4 bq[4];
    load8(av, Ap, (size_t)16 * CC);
#pragma unroll
    for (int j = 0; j < 4; ++j) bq[j] = *(const uint4*)(Bp + j * 8);
    writeA(av, a_s[0], a_r0, a_f4);
#pragma unroll
    for (int j = 0; j < 4; ++j)
        *(uint4*)&b_s[0][br * 32 + ((((bh << 2) + j) ^ (br & 7)) << 2)] = bq[j];
    __syncthreads();

    for (int kc = 0; kc < 4; ++kc) {
        const int cur = kc & 1;
        if (kc < 3) {
            load8(av, Ap + (kc + 1) * 64, (size_t)16 * CC);
#pragma unroll
            for (int j = 0; j < 4; ++j)
                bq[j] = *(const uint4*)(Bp + (kc + 1) * 64 + j * 8);
        }
        compute_tile(a_s[cur], b_s[cur], acc, lane, wm, wn);
        if (kc < 3) {
            writeA(av, a_s[cur ^ 1], a_r0, a_f4);
#pragma unroll
            for (int j = 0; j < 4; ++j)
                *(uint4*)&b_s[cur ^ 1][br * 32 + ((((bh << 2) + j) ^ (br & 7)) << 2)] = bq[j];
            __syncthreads();
        }
    }

    const int l_base = lb * 128 + wn * 64 + (lane & 15);
    const int o_base = ob * 128 + wm * 64 + ((lane >> 4) << 2);
#pragma unroll
    for (int mf = 0; mf < 4; ++mf) {
        int o0 = o_base + mf * 16;
        float4 bs = *(const float4*)(bias + o0);
#pragma unroll
        for (int nf = 0; nf < 4; ++nf) {
            int l = l_base + nf * 16;
            float* op = out + ((size_t)b * CC + o0) * LL + l;
            op[(size_t)0 * LL] = acc[mf][nf][0] + bs.x;
            op[(size_t)1 * LL] = acc[mf][nf][1] + bs.y;
            op[(size_t)2 * LL] = acc[mf][nf][2] + bs.z;
            op[(size_t)3 * LL] = acc[mf][nf][3] + bs.w;
        }
    }
}

// ---------------------------------------------------------------------------
// Fused softmax + offsets + bilinear sample + aggregation (branchless,
// batched gathers). v bf16 [(ba)][l][32]; agg bf16 l-major [B][L][256].
// XCD-locality: image ba = (bid&7)*8 + ((bid>>3)>>6).
// 4 threads/point, 8 channels each.
// ---------------------------------------------------------------------------
__global__ __launch_bounds__(256)
void sample_kernel(const uint16_t* __restrict__ v_samp,
                   const float* __restrict__ logits,
                   uint16_t* __restrict__ agg)
{
    const int bid  = blockIdx.x;         // 0..4095
    const int xcd  = bid & 7;
    const int rest = bid >> 3;
    const int img  = rest >> 6;
    const int lt   = rest & 63;
    const int ba   = xcd * 8 + img;
    const int b = ba >> 3, a = ba & 7;

    const int t  = threadIdx.x;
    const int l  = lt * 64 + (t >> 2);
    const int d0 = (t & 3) * 8;

    // softmax over N=4
    const float* la = logits + ((size_t)b * 96 + a * 4) * LL + l;
    float e0 = la[0], e1 = la[(size_t)LL], e2 = la[(size_t)2 * LL], e3 = la[(size_t)3 * LL];
    float m = fmaxf(fmaxf(e0, e1), fmaxf(e2, e3));
    e0 = expf(e0 - m); e1 = expf(e1 - m); e2 = expf(e2 - m); e3 = expf(e3 - m);
    float inv = 1.0f / (e0 + e1 + e2 + e3);
    float attn[4] = {e0 * inv, e1 * inv, e2 * inv, e3 * inv};

    const int gi = l >> 6, gj = l & 63;
    float ry = (gi + 0.5f) * (2.0f / 63.0f) - 1.0f;
    float rx = (gj + 0.5f) * (2.0f / 63.0f) - 1.0f;
    const float* lo = logits + ((size_t)b * 96 + 32 + a * 8) * LL + l;

    // precompute 16 (offset, weight) pairs; OOB -> weight 0, clamped address
    int   offs[16];
    float wgt[16];
#pragma unroll
    for (int n = 0; n < 4; ++n) {
        float py = ry + lo[(size_t)(n * 2 + 0) * LL];
        float px = rx + lo[(size_t)(n * 2 + 1) * LL];
        float y = (py + 1.0f) * 0.5f * 63.0f;
        float x = (px + 1.0f) * 0.5f * 63.0f;
        float yf = floorf(y), xf = floorf(x);
        int y0i = (int)yf, x0i = (int)xf;
        float fy = y - yf, fx = x - xf;
        float wts[4] = {(1.f - fy) * (1.f - fx), (1.f - fy) * fx,
                        fy * (1.f - fx),         fy * fx};
#pragma unroll
        for (int c2 = 0; c2 < 4; ++c2) {
            int yi = y0i + (c2 >> 1);
            int xi = x0i + (c2 & 1);
            bool valid = (yi >= 0) & (yi < HH) & (xi >= 0) & (xi < WW);
            int yc = min(max(yi, 0), HH - 1);
            int xc = min(max(xi, 0), WW - 1);
            wgt[n * 4 + c2]  = valid ? attn[n] * wts[c2] : 0.0f;
            offs[n * 4 + c2] = (yc * WW + xc) * DD;
        }
    }

    float acc[8];
#pragma unroll
    for (int q = 0; q < 8; ++q) acc[q] = 0.f;

    const uint16_t* vb = v_samp + (size_t)ba * LL * DD + d0;
#pragma unroll
    for (int g = 0; g < 2; ++g) {
        uint4 rv[8];
#pragma unroll
        for (int i = 0; i < 8; ++i)
            rv[i] = *(const uint4*)(vb + offs[g * 8 + i]);
#pragma unroll
        for (int i = 0; i < 8; ++i) {
            float w = wgt[g * 8 + i];
            acc[0] += w * bf_lo(rv[i].x); acc[1] += w * bf_hi(rv[i].x);
            acc[2] += w * bf_lo(rv[i].y); acc[3] += w * bf_hi(rv[i].y);
            acc[4] += w * bf_lo(rv[i].z); acc[5] += w * bf_hi(rv[i].z);
            acc[6] += w * bf_lo(rv[i].w); acc[7] += w * bf_hi(rv[i].w);
        }
    }

    uint32_t p0 = pk_bf16(acc[0], acc[1]);
    uint32_t p1 = pk_bf16(acc[2], acc[3]);
    uint32_t p2 = pk_bf16(acc[4], acc[5]);
    uint32_t p3 = pk_bf16(acc[6], acc[7]);
    *(uint4*)(agg + ((size_t)b * LL + l) * CC + a * DD + d0) =
        make_uint4(p0, p1, p2, p3);
}

extern "C" void kernel_launch(void* const* d_in, const int* in_sizes, int n_in,
                              void* d_out, int out_size, void* d_ws, size_t ws_size,
                              hipStream_t stream) {
    const float* x     = (const float*)d_in[0];
    const float* w_att = (const float*)d_in[1];
    const float* b_att = (const float*)d_in[2];
    const float* w_off = (const float*)d_in[3];
    const float* b_off = (const float*)d_in[4];
    const float* w_v   = (const float*)d_in[5];
    const float* b_v   = (const float*)d_in[6];
    const float* w_out = (const float*)d_in[7];
    const float* b_out = (const float*)d_in[8];
    float* out = (float*)d_out;

    float* ws      = (float*)d_ws;
    float* logits  = ws;                                   // B*96*L f32
    uint16_t* agg  = (uint16_t*)(logits + (size_t)BQ * 96 * LL);  // B*L*256 bf16
    uint16_t* v_samp = (uint16_t*)d_out;  // d_out reused: v bf16 (16.7MB < 33.5MB),
                                          // dead before gemm_out writes fp32 out

    dim3 blk(256);
    gemm_attoff<<<dim3(64, BQ), blk, 0, stream>>>(x, w_att, w_off, b_att, b_off, logits);
    gemm_v<<<dim3(256, 2), blk, 0, stream>>>(x, w_v, b_v, v_samp);
    sample_kernel<<<dim3(4096), blk, 0, stream>>>(v_samp, logits, agg);
    gemm_out<<<dim3(256, 2), blk, 0, stream>>>(agg, w_out, b_out, out);
}